// Round 4
// baseline (474.221 us; speedup 1.0000x reference)
//
#include <hip/hip_runtime.h>

// Problem: B=2, L=2048, E=1024, H=16, D=64
// softmax over QUERY axis (columns of the [L,M] score matrix per head).
//
// Softmax algebra: P[l,m] = 2^(S'[l,m] - d2_m), S' = log2(e)*S (folded into Q),
// d2_m = log2(sum_l 2^(S'[l,m])).  No max-subtraction: S ~ N(0,64) so
// |S'| < ~80 << 127 (f32 exp2 range); sum <= 2048*2^80 < f32 max.
//
// k_stats / k_attn: Q/K/V MFMA fragments read DIRECTLY from global (K+V =
// 512KB/head, L2-resident; round-3 counters: FETCH 12MB, HBM 5%).  Work is
// m-split (attn) / l-split (stats) 4 ways per 64-row group -- traffic-free
// (fragment loads amortize over the row group regardless of range split) --
// giving 4096 waves = 16 waves/CU (round-3 was 4 waves/CU, latency-bound).
// Partials combined exactly at kernel end via small LDS reductions.

typedef _Float16 f16x8 __attribute__((ext_vector_type(8)));
typedef _Float16 f16x4 __attribute__((ext_vector_type(4)));
typedef __fp16 fp16x2 __attribute__((ext_vector_type(2)));  // cvt_pkrtz ret type
typedef float f32x4 __attribute__((ext_vector_type(4)));

#define MFMA(a, b, c) __builtin_amdgcn_mfma_f32_16x16x32_f16((a), (b), (c), 0, 0, 0)
#define EXP2(x) __builtin_amdgcn_exp2f(x)
#define LOG2E 1.44269504088896340736f

// ---------------------------------------------------------------------------
// Kernel 1: fp32 -> f16 convert of x  (4096x1024)
// ---------------------------------------------------------------------------
__global__ __launch_bounds__(256) void k_convert_x(const float* __restrict__ x,
                                                   _Float16* __restrict__ xb) {
    int i = (blockIdx.x * 256 + threadIdx.x) * 4;
    float4 f = *(const float4*)(x + i);
    f16x4 o = {(_Float16)f.x, (_Float16)f.y, (_Float16)f.z, (_Float16)f.w};
    *(f16x4*)(xb + i) = o;
}

// ---------------------------------------------------------------------------
// Kernel 2: W (k-major [E][E]) -> W^T f16 ([3*E rows = n][E cols = k])
// ---------------------------------------------------------------------------
__global__ __launch_bounds__(256) void k_convert_wt(const float* __restrict__ Wq,
                                                    const float* __restrict__ Wk,
                                                    const float* __restrict__ Wv,
                                                    _Float16* __restrict__ wbt) {
    const int jz = blockIdx.z;
    const float* W = (jz == 0) ? Wq : (jz == 1) ? Wk : Wv;
    __shared__ float tile[64][65];
    const int k0 = blockIdx.y * 64, n0 = blockIdx.x * 64;
    for (int e = threadIdx.x; e < 4096; e += 256) {
        int r = e >> 6, c = e & 63;
        tile[r][c] = W[(k0 + r) * 1024 + n0 + c];
    }
    __syncthreads();
    for (int e = threadIdx.x; e < 4096; e += 256) {
        int r = e >> 6, c = e & 63;
        wbt[((size_t)jz * 1024 + n0 + r) * 1024 + k0 + c] = (_Float16)tile[c][r];
    }
}

// ---------------------------------------------------------------------------
// Kernel 3: fused QKV projection GEMM (Q scaled by log2e for exp2 downstream).
// ---------------------------------------------------------------------------
__global__ __launch_bounds__(256) void k_proj_gemm(const _Float16* __restrict__ xb,
                                                   const _Float16* __restrict__ wbt,
                                                   const float* __restrict__ bq,
                                                   const float* __restrict__ bk,
                                                   const float* __restrict__ bv,
                                                   _Float16* __restrict__ Qb,
                                                   _Float16* __restrict__ Kb,
                                                   _Float16* __restrict__ Vt) {
    const int n0 = blockIdx.x * 128;
    const int m0 = blockIdx.y * 128;
    __shared__ _Float16 As[128][40];
    __shared__ _Float16 Bs[128][40];
    const int tid = threadIdx.x;
    const int lane = tid & 63, wv = tid >> 6;
    const int l15 = lane & 15, quad = lane >> 4;
    const int wr = wv >> 1, wc = wv & 1;

    f32x4 acc[4][4] = {};
    for (int k0 = 0; k0 < 1024; k0 += 32) {
        __syncthreads();
        for (int j = 0; j < 2; ++j) {
            int chunk = tid + 256 * j;
            int row = chunk >> 2, c = chunk & 3;
            *(uint4*)&As[row][c * 8] = *(const uint4*)&xb[(size_t)(m0 + row) * 1024 + k0 + c * 8];
            *(uint4*)&Bs[row][c * 8] = *(const uint4*)&wbt[(size_t)(n0 + row) * 1024 + k0 + c * 8];
        }
        __syncthreads();
        f16x8 af[4], bf[4];
        for (int i = 0; i < 4; ++i) {
            af[i] = *(const f16x8*)&As[wr * 64 + i * 16 + l15][quad * 8];
            bf[i] = *(const f16x8*)&Bs[wc * 64 + i * 16 + l15][quad * 8];
        }
        for (int i = 0; i < 4; ++i)
            for (int j = 0; j < 4; ++j)
                acc[i][j] = MFMA(af[i], bf[j], acc[i][j]);
    }

    const int proj = n0 >> 10;
    const float* bias = (proj == 0) ? bq : (proj == 1) ? bk : bv;
    const float scale = (proj == 0) ? LOG2E : 1.0f;
    for (int j = 0; j < 4; ++j) {
        int n = n0 + wc * 64 + j * 16 + l15;
        int nn = n & 1023;
        float bsv = bias[nn];
        int h = nn >> 6, d = nn & 63;
        for (int i = 0; i < 4; ++i) {
            for (int r = 0; r < 4; ++r) {
                int t = m0 + wr * 64 + i * 16 + quad * 4 + r;
                int b = t >> 11, l = t & 2047;
                _Float16 val = (_Float16)((acc[i][j][r] + bsv) * scale);
                int bh = b * 16 + h;
                if (proj == 0)
                    Qb[((size_t)bh * 2048 + l) * 64 + d] = val;
                else if (proj == 1)
                    Kb[((size_t)bh * 2048 + l) * 64 + d] = val;
                else
                    Vt[((size_t)bh * 64 + d) * 2048 + l] = val;
            }
        }
    }
}

// ---------------------------------------------------------------------------
// Kernel 4: column stats d2_m = log2(sum_l 2^(S'[l,m])).
// Block = 64 m-cols of one head; 4 waves each own an l-quarter (512 l,
// 16 iters of 32).  K frags loop-invariant in regs, Q register-prefetched.
// Partial exp-sums combined exactly in LDS at the end (sum is associative).
// 1024 blocks -> 16 waves/CU.
// ---------------------------------------------------------------------------
__global__ __launch_bounds__(256, 4) void k_stats(const _Float16* __restrict__ Qb,
                                                  const _Float16* __restrict__ Kb,
                                                  float* __restrict__ d2) {
    __shared__ float sred[4][4][64];            // [wave][s][lane] partials, 4KB
    const int id = blockIdx.x;                  // 1024 blocks
    const int wk = (id & 7) * 128 + (id >> 3);  // XCD swizzle: same-head -> same XCD
    const int bh = wk >> 5;                     // 32 heads
    const int mt = wk & 31;                     // 32 m-tiles of 64
    const int lane = threadIdx.x & 63, wv = threadIdx.x >> 6;
    const int l15 = lane & 15, quad = lane >> 4;
    const int m0 = mt * 64;
    const int lbase = wv * 512;                 // wave's l-quarter
    const size_t base = (size_t)bh * 2048 * 64;
    const _Float16* Kp = Kb + base;
    const _Float16* Qp = Qb + base;

    // K fragments (X-operand rows = m): loop-invariant
    f16x8 bf[4][2];
    #pragma unroll
    for (int s = 0; s < 4; ++s) {
        bf[s][0] = *(const f16x8*)&Kp[(size_t)(m0 + s * 16 + l15) * 64 + quad * 8];
        bf[s][1] = *(const f16x8*)&Kp[(size_t)(m0 + s * 16 + l15) * 64 + 32 + quad * 8];
    }
    float rs[4] = {0.f, 0.f, 0.f, 0.f};
    f16x8 qc[2][2], qn[2][2];
    #pragma unroll
    for (int lt = 0; lt < 2; ++lt) {
        qc[lt][0] = *(const f16x8*)&Qp[(size_t)(lbase + lt * 16 + l15) * 64 + quad * 8];
        qc[lt][1] = *(const f16x8*)&Qp[(size_t)(lbase + lt * 16 + l15) * 64 + 32 + quad * 8];
    }
    for (int lr = 0; lr < 512; lr += 32) {
        int l1 = lbase + ((lr + 32) & 511);  // wrap: last prefetch unused
        #pragma unroll
        for (int lt = 0; lt < 2; ++lt) {
            qn[lt][0] = *(const f16x8*)&Qp[(size_t)(l1 + lt * 16 + l15) * 64 + quad * 8];
            qn[lt][1] = *(const f16x8*)&Qp[(size_t)(l1 + lt * 16 + l15) * 64 + 32 + quad * 8];
        }
        #pragma unroll
        for (int s = 0; s < 4; ++s)
            #pragma unroll
            for (int lt = 0; lt < 2; ++lt) {
                f32x4 a = {};
                a = MFMA(qc[lt][0], bf[s][0], a);
                a = MFMA(qc[lt][1], bf[s][1], a);
                rs[s] += EXP2(a[0]) + EXP2(a[1]) + EXP2(a[2]) + EXP2(a[3]);
            }
        #pragma unroll
        for (int lt = 0; lt < 2; ++lt) {
            qc[lt][0] = qn[lt][0];
            qc[lt][1] = qn[lt][1];
        }
    }
    // combine wave partials (exact: plain sum)
    #pragma unroll
    for (int s = 0; s < 4; ++s) sred[wv][s][lane] = rs[s];
    __syncthreads();
    if (wv == 0) {
        #pragma unroll
        for (int s = 0; s < 4; ++s) {
            float t = sred[0][s][lane] + sred[1][s][lane] + sred[2][s][lane] + sred[3][s][lane];
            t += __shfl_xor(t, 16, 64);
            t += __shfl_xor(t, 32, 64);
            rs[s] = t;
        }
        float myz = (quad == 0) ? rs[0] : (quad == 1) ? rs[1] : (quad == 2) ? rs[2] : rs[3];
        d2[bh * 2048 + m0 + quad * 16 + l15] = __builtin_amdgcn_logf(myz);  // v_log = log2
    }
}

// ---------------------------------------------------------------------------
// Kernel 5: output. Block = 64 l-rows of one head; 4 waves each own an
// m-quarter (512 m, 16 iters of 32) -- traffic-free split, partial O summed
// exactly at the end (PV linear in m).  Zero barriers in the main loop.
// K/V/d2 register-prefetched one iter ahead.  Swapped QK -> packed P ->
// ds_write_b64; swapped PV -> float4-coalesced epilogue.
// 1024 blocks -> 16 waves/CU (round-3 occupancy fix).
// ---------------------------------------------------------------------------
__global__ __launch_bounds__(256, 4) void k_attn(const _Float16* __restrict__ Qb,
                                                 const _Float16* __restrict__ Kb,
                                                 const _Float16* __restrict__ Vt,
                                                 const float* __restrict__ d2,
                                                 float* __restrict__ out) {
    __shared__ _Float16 Ps[4][64][40];          // per-wave P scratch [l][m], 20 KB
    __shared__ f32x4 obuf[3][4][64];            // [wave-1][lt][lane] combine, 12 KB
    const int id = blockIdx.x;                  // 1024 blocks
    const int wk = (id & 7) * 128 + (id >> 3);  // XCD swizzle
    const int bh = wk >> 5;                     // 32 heads
    const int ltile = wk & 31;                  // 32 l-tiles of 64
    const int b = bh >> 4, h = bh & 15;
    const int lane = threadIdx.x & 63, wv = threadIdx.x >> 6;
    const int l15 = lane & 15, quad = lane >> 4;
    const int l0 = ltile * 64;                  // block's 64 l-rows
    const int mbase = wv * 512;                 // wave's m-quarter
    const size_t base = (size_t)bh * 2048 * 64;
    const _Float16* Qp = Qb + base;
    const _Float16* Kp = Kb + base;
    const _Float16* Vp = Vt + base;
    const float* d2p = d2 + bh * 2048;

    // Q fragments (Y-operand rows = l): loop-invariant, shared rows per block
    f16x8 qf[4][2];
    #pragma unroll
    for (int lt = 0; lt < 4; ++lt) {
        qf[lt][0] = *(const f16x8*)&Qp[(size_t)(l0 + lt * 16 + l15) * 64 + quad * 8];
        qf[lt][1] = *(const f16x8*)&Qp[(size_t)(l0 + lt * 16 + l15) * 64 + 32 + quad * 8];
    }
    f32x4 oacc[4][4] = {};  // [dt][lt]: lane holds out[d=dt*16+quad*4+r][l=lt*16+l15]

    f16x8 kf[2][2], nkf[2][2], vf[4], nvf[4];
    f32x4 dv[2], ndv[2];
    #pragma unroll
    for (int s = 0; s < 2; ++s) {
        kf[s][0] = *(const f16x8*)&Kp[(size_t)(mbase + s * 16 + l15) * 64 + quad * 8];
        kf[s][1] = *(const f16x8*)&Kp[(size_t)(mbase + s * 16 + l15) * 64 + 32 + quad * 8];
        dv[s] = *(const f32x4*)&d2p[mbase + s * 16 + quad * 4];
    }
    #pragma unroll
    for (int dt = 0; dt < 4; ++dt)
        vf[dt] = *(const f16x8*)&Vp[(size_t)(dt * 16 + l15) * 2048 + mbase + quad * 8];

    for (int mr = 0; mr < 512; mr += 32) {
        const int m0 = mbase + mr;
        const int m1 = mbase + ((mr + 32) & 511);  // wrap: last prefetch unused
        // prefetch next-iter K/V/d2 (a full iteration of latency cover)
        #pragma unroll
        for (int s = 0; s < 2; ++s) {
            nkf[s][0] = *(const f16x8*)&Kp[(size_t)(m1 + s * 16 + l15) * 64 + quad * 8];
            nkf[s][1] = *(const f16x8*)&Kp[(size_t)(m1 + s * 16 + l15) * 64 + 32 + quad * 8];
            ndv[s] = *(const f32x4*)&d2p[m1 + s * 16 + quad * 4];
        }
        #pragma unroll
        for (int dt = 0; dt < 4; ++dt)
            nvf[dt] = *(const f16x8*)&Vp[(size_t)(dt * 16 + l15) * 2048 + m1 + quad * 8];
        // QK^T swapped: D[m = quad*4+r][l = l15]; P = 2^(S'-d2), pack, b64 store
        #pragma unroll
        for (int s = 0; s < 2; ++s)
            #pragma unroll
            for (int lt = 0; lt < 4; ++lt) {
                f32x4 a = {};
                a = MFMA(kf[s][0], qf[lt][0], a);
                a = MFMA(kf[s][1], qf[lt][1], a);
                union { fp16x2 h[2]; f16x4 v; } u;
                u.h[0] = __builtin_amdgcn_cvt_pkrtz(EXP2(a[0] - dv[s][0]),
                                                    EXP2(a[1] - dv[s][1]));
                u.h[1] = __builtin_amdgcn_cvt_pkrtz(EXP2(a[2] - dv[s][2]),
                                                    EXP2(a[3] - dv[s][3]));
                *(f16x4*)&Ps[wv][lt * 16 + l15][s * 16 + quad * 4] = u.v;
            }
        // PV swapped: oacc[dt][lt] += mfma(V-frag, P-frag); wave-private LDS,
        // lgkmcnt-ordered within the wave (no barrier).
        #pragma unroll
        for (int lt = 0; lt < 4; ++lt) {
            f16x8 pf = *(const f16x8*)&Ps[wv][lt * 16 + l15][quad * 8];
            #pragma unroll
            for (int dt = 0; dt < 4; ++dt)
                oacc[dt][lt] = MFMA(vf[dt], pf, oacc[dt][lt]);
        }
        // rotate prefetch
        #pragma unroll
        for (int s = 0; s < 2; ++s) {
            kf[s][0] = nkf[s][0];
            kf[s][1] = nkf[s][1];
            dv[s] = ndv[s];
        }
        #pragma unroll
        for (int dt = 0; dt < 4; ++dt) vf[dt] = nvf[dt];
    }
    // combine the 4 m-quarter partials (exact) one dt-slab at a time, then
    // wave 0 writes float4-coalesced output.
    #pragma unroll
    for (int dt = 0; dt < 4; ++dt) {
        if (wv > 0) {
            #pragma unroll
            for (int lt = 0; lt < 4; ++lt) obuf[wv - 1][lt][lane] = oacc[dt][lt];
        }
        __syncthreads();
        if (wv == 0) {
            #pragma unroll
            for (int lt = 0; lt < 4; ++lt) {
                f32x4 o = oacc[dt][lt] + obuf[0][lt][lane] + obuf[1][lt][lane] + obuf[2][lt][lane];
                int l = l0 + lt * 16 + l15;
                float4 o4 = {o[0], o[1], o[2], o[3]};
                *(float4*)&out[((size_t)(b * 2048 + l)) * 1024 + h * 64 + dt * 16 + quad * 4] = o4;
            }
        }
        __syncthreads();
    }
}

// ---------------------------------------------------------------------------
// Workspace layout (bytes):
//  0        xb   : 4096*1024 f16          = 8 MB
//  8 MB     wbt  : 3072*1024 f16          = 6 MB
// 14 MB     Qb   : 32*2048*64 f16         = 8 MB   (pre-scaled by log2e)
// 22 MB     Kb   : 32*2048*64 f16         = 8 MB
// 30 MB     Vt   : 32*64*2048 f16         = 8 MB
// 38 MB     d2   : 32*2048 f32            = 256 KB (log2 of column expsum)
// ---------------------------------------------------------------------------
extern "C" void kernel_launch(void* const* d_in, const int* in_sizes, int n_in,
                              void* d_out, int out_size, void* d_ws, size_t ws_size,
                              hipStream_t stream) {
    const float* x  = (const float*)d_in[0];
    const float* Wq = (const float*)d_in[1];
    const float* bq = (const float*)d_in[2];
    const float* Wk = (const float*)d_in[3];
    const float* bk = (const float*)d_in[4];
    const float* Wv = (const float*)d_in[5];
    const float* bv = (const float*)d_in[6];
    float* out = (float*)d_out;

    char* w = (char*)d_ws;
    _Float16* xb  = (_Float16*)(w);
    _Float16* wbt = (_Float16*)(w + (size_t)(8 << 20));
    _Float16* Qb  = (_Float16*)(w + (size_t)(14 << 20));
    _Float16* Kb  = (_Float16*)(w + (size_t)(22 << 20));
    _Float16* Vt  = (_Float16*)(w + (size_t)(30 << 20));
    float* d2     = (float*)(w + (size_t)(38 << 20));

    k_convert_x<<<4096, 256, 0, stream>>>(x, xb);
    k_convert_wt<<<dim3(16, 16, 3), 256, 0, stream>>>(Wq, Wk, Wv, wbt);
    k_proj_gemm<<<dim3(24, 32), 256, 0, stream>>>(xb, wbt, bq, bk, bv, Qb, Kb, Vt);
    k_stats<<<1024, 256, 0, stream>>>(Qb, Kb, d2);
    k_attn<<<1024, 256, 0, stream>>>(Qb, Kb, Vt, d2, out);
}

// Round 5
// 277.879 us; speedup vs baseline: 1.7066x; 1.7066x over previous
//
#include <hip/hip_runtime.h>

// Problem: B=2, L=2048, E=1024, H=16, D=64
// softmax over QUERY axis (columns of the [L,M] score matrix per head).
//
// Softmax algebra: P[l,m] = 2^(S'[l,m] - d2_m), S' = log2(e)*S (folded into Q),
// d2_m = log2(sum_l 2^(S'[l,m])).  No max-subtraction: S ~ N(0,64) so
// |S'| < ~80 << 127 (f32 exp2 range); sum <= 2048*2^80 < f32 max.
//
// k_stats / k_attn: Q/K/V MFMA fragments read DIRECTLY from global (K+V =
// 512KB/head, L2-resident).  Work is m-split (attn) / l-split (stats) 4 ways
// per 64-row group across waves; partials combined exactly at kernel end.
// Grid = 1024 blocks (4 blocks/CU).  NOTE (round-4 lesson): gfx950 has a
// UNIFIED VGPR/AGPR file -- __launch_bounds__(256,4) = 128-reg total budget
// forced 90+ regs of spill (706 MB scratch writes).  Use (256,2) = 256-reg
// budget (no spill); occupancy comes from ACTUAL usage (~170 -> 3 waves/SIMD).

typedef _Float16 f16x8 __attribute__((ext_vector_type(8)));
typedef _Float16 f16x4 __attribute__((ext_vector_type(4)));
typedef __fp16 fp16x2 __attribute__((ext_vector_type(2)));  // cvt_pkrtz ret type
typedef float f32x4 __attribute__((ext_vector_type(4)));

#define MFMA(a, b, c) __builtin_amdgcn_mfma_f32_16x16x32_f16((a), (b), (c), 0, 0, 0)
#define EXP2(x) __builtin_amdgcn_exp2f(x)
#define LOG2E 1.44269504088896340736f

// ---------------------------------------------------------------------------
// Kernel 1: fp32 -> f16 convert of x  (4096x1024)
// ---------------------------------------------------------------------------
__global__ __launch_bounds__(256) void k_convert_x(const float* __restrict__ x,
                                                   _Float16* __restrict__ xb) {
    int i = (blockIdx.x * 256 + threadIdx.x) * 4;
    float4 f = *(const float4*)(x + i);
    f16x4 o = {(_Float16)f.x, (_Float16)f.y, (_Float16)f.z, (_Float16)f.w};
    *(f16x4*)(xb + i) = o;
}

// ---------------------------------------------------------------------------
// Kernel 2: W (k-major [E][E]) -> W^T f16 ([3*E rows = n][E cols = k])
// ---------------------------------------------------------------------------
__global__ __launch_bounds__(256) void k_convert_wt(const float* __restrict__ Wq,
                                                    const float* __restrict__ Wk,
                                                    const float* __restrict__ Wv,
                                                    _Float16* __restrict__ wbt) {
    const int jz = blockIdx.z;
    const float* W = (jz == 0) ? Wq : (jz == 1) ? Wk : Wv;
    __shared__ float tile[64][65];
    const int k0 = blockIdx.y * 64, n0 = blockIdx.x * 64;
    for (int e = threadIdx.x; e < 4096; e += 256) {
        int r = e >> 6, c = e & 63;
        tile[r][c] = W[(k0 + r) * 1024 + n0 + c];
    }
    __syncthreads();
    for (int e = threadIdx.x; e < 4096; e += 256) {
        int r = e >> 6, c = e & 63;
        wbt[((size_t)jz * 1024 + n0 + r) * 1024 + k0 + c] = (_Float16)tile[c][r];
    }
}

// ---------------------------------------------------------------------------
// Kernel 3: fused QKV projection GEMM (Q scaled by log2e for exp2 downstream).
// ---------------------------------------------------------------------------
__global__ __launch_bounds__(256) void k_proj_gemm(const _Float16* __restrict__ xb,
                                                   const _Float16* __restrict__ wbt,
                                                   const float* __restrict__ bq,
                                                   const float* __restrict__ bk,
                                                   const float* __restrict__ bv,
                                                   _Float16* __restrict__ Qb,
                                                   _Float16* __restrict__ Kb,
                                                   _Float16* __restrict__ Vt) {
    const int n0 = blockIdx.x * 128;
    const int m0 = blockIdx.y * 128;
    __shared__ _Float16 As[128][40];
    __shared__ _Float16 Bs[128][40];
    const int tid = threadIdx.x;
    const int lane = tid & 63, wv = tid >> 6;
    const int l15 = lane & 15, quad = lane >> 4;
    const int wr = wv >> 1, wc = wv & 1;

    f32x4 acc[4][4] = {};
    for (int k0 = 0; k0 < 1024; k0 += 32) {
        __syncthreads();
        for (int j = 0; j < 2; ++j) {
            int chunk = tid + 256 * j;
            int row = chunk >> 2, c = chunk & 3;
            *(uint4*)&As[row][c * 8] = *(const uint4*)&xb[(size_t)(m0 + row) * 1024 + k0 + c * 8];
            *(uint4*)&Bs[row][c * 8] = *(const uint4*)&wbt[(size_t)(n0 + row) * 1024 + k0 + c * 8];
        }
        __syncthreads();
        f16x8 af[4], bf[4];
        for (int i = 0; i < 4; ++i) {
            af[i] = *(const f16x8*)&As[wr * 64 + i * 16 + l15][quad * 8];
            bf[i] = *(const f16x8*)&Bs[wc * 64 + i * 16 + l15][quad * 8];
        }
        for (int i = 0; i < 4; ++i)
            for (int j = 0; j < 4; ++j)
                acc[i][j] = MFMA(af[i], bf[j], acc[i][j]);
    }

    const int proj = n0 >> 10;
    const float* bias = (proj == 0) ? bq : (proj == 1) ? bk : bv;
    const float scale = (proj == 0) ? LOG2E : 1.0f;
    for (int j = 0; j < 4; ++j) {
        int n = n0 + wc * 64 + j * 16 + l15;
        int nn = n & 1023;
        float bsv = bias[nn];
        int h = nn >> 6, d = nn & 63;
        for (int i = 0; i < 4; ++i) {
            for (int r = 0; r < 4; ++r) {
                int t = m0 + wr * 64 + i * 16 + quad * 4 + r;
                int b = t >> 11, l = t & 2047;
                _Float16 val = (_Float16)((acc[i][j][r] + bsv) * scale);
                int bh = b * 16 + h;
                if (proj == 0)
                    Qb[((size_t)bh * 2048 + l) * 64 + d] = val;
                else if (proj == 1)
                    Kb[((size_t)bh * 2048 + l) * 64 + d] = val;
                else
                    Vt[((size_t)bh * 64 + d) * 2048 + l] = val;
            }
        }
    }
}

// ---------------------------------------------------------------------------
// Kernel 4: column stats d2_m = log2(sum_l 2^(S'[l,m])).
// Block = 64 m-cols of one head; 4 waves each own an l-quarter (512 l,
// 16 iters of 32).  K frags loop-invariant in regs, Q register-prefetched.
// Partial exp-sums combined exactly in LDS at the end.  1024 blocks.
// ---------------------------------------------------------------------------
__global__ __launch_bounds__(256, 2) void k_stats(const _Float16* __restrict__ Qb,
                                                  const _Float16* __restrict__ Kb,
                                                  float* __restrict__ d2) {
    __shared__ float sred[4][4][64];            // [wave][s][lane] partials, 4KB
    const int id = blockIdx.x;                  // 1024 blocks
    const int wk = (id & 7) * 128 + (id >> 3);  // XCD swizzle: same-head -> same XCD
    const int bh = wk >> 5;                     // 32 heads
    const int mt = wk & 31;                     // 32 m-tiles of 64
    const int lane = threadIdx.x & 63, wv = threadIdx.x >> 6;
    const int l15 = lane & 15, quad = lane >> 4;
    const int m0 = mt * 64;
    const int lbase = wv * 512;                 // wave's l-quarter
    const size_t base = (size_t)bh * 2048 * 64;
    const _Float16* Kp = Kb + base;
    const _Float16* Qp = Qb + base;

    // K fragments (X-operand rows = m): loop-invariant
    f16x8 bf[4][2];
    #pragma unroll
    for (int s = 0; s < 4; ++s) {
        bf[s][0] = *(const f16x8*)&Kp[(size_t)(m0 + s * 16 + l15) * 64 + quad * 8];
        bf[s][1] = *(const f16x8*)&Kp[(size_t)(m0 + s * 16 + l15) * 64 + 32 + quad * 8];
    }
    float rs[4] = {0.f, 0.f, 0.f, 0.f};
    f16x8 qc[2][2], qn[2][2];
    #pragma unroll
    for (int lt = 0; lt < 2; ++lt) {
        qc[lt][0] = *(const f16x8*)&Qp[(size_t)(lbase + lt * 16 + l15) * 64 + quad * 8];
        qc[lt][1] = *(const f16x8*)&Qp[(size_t)(lbase + lt * 16 + l15) * 64 + 32 + quad * 8];
    }
    for (int lr = 0; lr < 512; lr += 32) {
        int l1 = lbase + ((lr + 32) & 511);  // wrap: last prefetch unused
        #pragma unroll
        for (int lt = 0; lt < 2; ++lt) {
            qn[lt][0] = *(const f16x8*)&Qp[(size_t)(l1 + lt * 16 + l15) * 64 + quad * 8];
            qn[lt][1] = *(const f16x8*)&Qp[(size_t)(l1 + lt * 16 + l15) * 64 + 32 + quad * 8];
        }
        #pragma unroll
        for (int s = 0; s < 4; ++s)
            #pragma unroll
            for (int lt = 0; lt < 2; ++lt) {
                f32x4 a = {};
                a = MFMA(qc[lt][0], bf[s][0], a);
                a = MFMA(qc[lt][1], bf[s][1], a);
                rs[s] += EXP2(a[0]) + EXP2(a[1]) + EXP2(a[2]) + EXP2(a[3]);
            }
        #pragma unroll
        for (int lt = 0; lt < 2; ++lt) {
            qc[lt][0] = qn[lt][0];
            qc[lt][1] = qn[lt][1];
        }
    }
    // combine wave partials (exact: plain sum)
    #pragma unroll
    for (int s = 0; s < 4; ++s) sred[wv][s][lane] = rs[s];
    __syncthreads();
    if (wv == 0) {
        #pragma unroll
        for (int s = 0; s < 4; ++s) {
            float t = sred[0][s][lane] + sred[1][s][lane] + sred[2][s][lane] + sred[3][s][lane];
            t += __shfl_xor(t, 16, 64);
            t += __shfl_xor(t, 32, 64);
            rs[s] = t;
        }
        float myz = (quad == 0) ? rs[0] : (quad == 1) ? rs[1] : (quad == 2) ? rs[2] : rs[3];
        d2[bh * 2048 + m0 + quad * 16 + l15] = __builtin_amdgcn_logf(myz);  // v_log = log2
    }
}

// ---------------------------------------------------------------------------
// Kernel 5: output. Block = 64 l-rows of one head; 4 waves each own an
// m-quarter (512 m, 16 iters of 32) -- traffic-free split, partial O summed
// exactly at the end (PV linear in m).  Zero barriers in the main loop.
// No explicit prefetch (round-4 lesson: register budget; 2-3 waves/SIMD TLP
// hides the L2-hit latency instead).  kf live only in the QK phase, vf only
// in PV.  Swapped QK -> packed P -> ds_write_b64; swapped PV -> float4
// epilogue.  1024 blocks.
// ---------------------------------------------------------------------------
__global__ __launch_bounds__(256, 2) void k_attn(const _Float16* __restrict__ Qb,
                                                 const _Float16* __restrict__ Kb,
                                                 const _Float16* __restrict__ Vt,
                                                 const float* __restrict__ d2,
                                                 float* __restrict__ out) {
    __shared__ _Float16 Ps[4][64][40];          // per-wave P scratch [l][m], 20 KB
    __shared__ f32x4 obuf[3][4][64];            // [wave-1][lt][lane] combine, 12 KB
    const int id = blockIdx.x;                  // 1024 blocks
    const int wk = (id & 7) * 128 + (id >> 3);  // XCD swizzle
    const int bh = wk >> 5;                     // 32 heads
    const int ltile = wk & 31;                  // 32 l-tiles of 64
    const int b = bh >> 4, h = bh & 15;
    const int lane = threadIdx.x & 63, wv = threadIdx.x >> 6;
    const int l15 = lane & 15, quad = lane >> 4;
    const int l0 = ltile * 64;                  // block's 64 l-rows
    const int mbase = wv * 512;                 // wave's m-quarter
    const size_t base = (size_t)bh * 2048 * 64;
    const _Float16* Qp = Qb + base;
    const _Float16* Kp = Kb + base;
    const _Float16* Vp = Vt + base;
    const float* d2p = d2 + bh * 2048;

    // Q fragments (Y-operand rows = l): loop-invariant
    f16x8 qf[4][2];
    #pragma unroll
    for (int lt = 0; lt < 4; ++lt) {
        qf[lt][0] = *(const f16x8*)&Qp[(size_t)(l0 + lt * 16 + l15) * 64 + quad * 8];
        qf[lt][1] = *(const f16x8*)&Qp[(size_t)(l0 + lt * 16 + l15) * 64 + 32 + quad * 8];
    }
    f32x4 oacc[4][4] = {};  // [dt][lt]: lane holds out[d=dt*16+quad*4+r][l=lt*16+l15]

    for (int mr = 0; mr < 512; mr += 32) {
        const int m0 = mbase + mr;
        // K fragments + d2 for this m-chunk (live through QK phase only)
        f16x8 kf[2][2];
        f32x4 dv[2];
        #pragma unroll
        for (int s = 0; s < 2; ++s) {
            kf[s][0] = *(const f16x8*)&Kp[(size_t)(m0 + s * 16 + l15) * 64 + quad * 8];
            kf[s][1] = *(const f16x8*)&Kp[(size_t)(m0 + s * 16 + l15) * 64 + 32 + quad * 8];
            dv[s] = *(const f32x4*)&d2p[m0 + s * 16 + quad * 4];
        }
        // QK^T swapped: D[m = quad*4+r][l = l15]; P = 2^(S'-d2), pack, b64 store
        #pragma unroll
        for (int s = 0; s < 2; ++s)
            #pragma unroll
            for (int lt = 0; lt < 4; ++lt) {
                f32x4 a = {};
                a = MFMA(kf[s][0], qf[lt][0], a);
                a = MFMA(kf[s][1], qf[lt][1], a);
                union { fp16x2 h[2]; f16x4 v; } u;
                u.h[0] = __builtin_amdgcn_cvt_pkrtz(EXP2(a[0] - dv[s][0]),
                                                    EXP2(a[1] - dv[s][1]));
                u.h[1] = __builtin_amdgcn_cvt_pkrtz(EXP2(a[2] - dv[s][2]),
                                                    EXP2(a[3] - dv[s][3]));
                *(f16x4*)&Ps[wv][lt * 16 + l15][s * 16 + quad * 4] = u.v;
            }
        // V fragments for this m-chunk (live through PV phase only)
        f16x8 vf[4];
        #pragma unroll
        for (int dt = 0; dt < 4; ++dt)
            vf[dt] = *(const f16x8*)&Vp[(size_t)(dt * 16 + l15) * 2048 + m0 + quad * 8];
        // PV swapped: oacc[dt][lt] += mfma(V-frag, P-frag); wave-private LDS,
        // lgkmcnt-ordered within the wave (no barrier).
        #pragma unroll
        for (int lt = 0; lt < 4; ++lt) {
            f16x8 pf = *(const f16x8*)&Ps[wv][lt * 16 + l15][quad * 8];
            #pragma unroll
            for (int dt = 0; dt < 4; ++dt)
                oacc[dt][lt] = MFMA(vf[dt], pf, oacc[dt][lt]);
        }
    }
    // combine the 4 m-quarter partials (exact) one dt-slab at a time, then
    // wave 0 writes float4-coalesced output.
    #pragma unroll
    for (int dt = 0; dt < 4; ++dt) {
        if (wv > 0) {
            #pragma unroll
            for (int lt = 0; lt < 4; ++lt) obuf[wv - 1][lt][lane] = oacc[dt][lt];
        }
        __syncthreads();
        if (wv == 0) {
            #pragma unroll
            for (int lt = 0; lt < 4; ++lt) {
                f32x4 o = oacc[dt][lt] + obuf[0][lt][lane] + obuf[1][lt][lane] + obuf[2][lt][lane];
                int l = l0 + lt * 16 + l15;
                float4 o4 = {o[0], o[1], o[2], o[3]};
                *(float4*)&out[((size_t)(b * 2048 + l)) * 1024 + h * 64 + dt * 16 + quad * 4] = o4;
            }
        }
        __syncthreads();
    }
}

// ---------------------------------------------------------------------------
// Workspace layout (bytes):
//  0        xb   : 4096*1024 f16          = 8 MB
//  8 MB     wbt  : 3072*1024 f16          = 6 MB
// 14 MB     Qb   : 32*2048*64 f16         = 8 MB   (pre-scaled by log2e)
// 22 MB     Kb   : 32*2048*64 f16         = 8 MB
// 30 MB     Vt   : 32*64*2048 f16         = 8 MB
// 38 MB     d2   : 32*2048 f32            = 256 KB (log2 of column expsum)
// ---------------------------------------------------------------------------
extern "C" void kernel_launch(void* const* d_in, const int* in_sizes, int n_in,
                              void* d_out, int out_size, void* d_ws, size_t ws_size,
                              hipStream_t stream) {
    const float* x  = (const float*)d_in[0];
    const float* Wq = (const float*)d_in[1];
    const float* bq = (const float*)d_in[2];
    const float* Wk = (const float*)d_in[3];
    const float* bk = (const float*)d_in[4];
    const float* Wv = (const float*)d_in[5];
    const float* bv = (const float*)d_in[6];
    float* out = (float*)d_out;

    char* w = (char*)d_ws;
    _Float16* xb  = (_Float16*)(w);
    _Float16* wbt = (_Float16*)(w + (size_t)(8 << 20));
    _Float16* Qb  = (_Float16*)(w + (size_t)(14 << 20));
    _Float16* Kb  = (_Float16*)(w + (size_t)(22 << 20));
    _Float16* Vt  = (_Float16*)(w + (size_t)(30 << 20));
    float* d2     = (float*)(w + (size_t)(38 << 20));

    k_convert_x<<<4096, 256, 0, stream>>>(x, xb);
    k_convert_wt<<<dim3(16, 16, 3), 256, 0, stream>>>(Wq, Wk, Wv, wbt);
    k_proj_gemm<<<dim3(24, 32), 256, 0, stream>>>(xb, wbt, bq, bk, bv, Qb, Kb, Vt);
    k_stats<<<1024, 256, 0, stream>>>(Qb, Kb, d2);
    k_attn<<<1024, 256, 0, stream>>>(Qb, Kb, Vt, d2, out);
}

// Round 6
// 258.350 us; speedup vs baseline: 1.8356x; 1.0756x over previous
//
#include <hip/hip_runtime.h>

// Problem: B=2, L=2048, E=1024, H=16, D=64
// softmax over QUERY axis (columns of the [L,M] score matrix per head).
//
// Softmax algebra: P[l,m] = 2^(S'[l,m] - d2_m), S' = log2(e)*S (folded into Q),
// d2_m = log2(sum_l 2^(S'[l,m])).  No max-subtraction: S ~ N(0,64) so
// |S'| < ~80 << 127 (f32 exp2 range); sum <= 2048*2^80 < f32 max.
//
// k_stats / k_attn: fragments read DIRECTLY from global (K+V = 512KB/head,
// L2-resident).  m-split (attn) / l-split (stats) 4 ways across waves;
// partials combined exactly at kernel end.  1024 blocks.
// Round-4 lesson: gfx950 unified VGPR/AGPR file -- (256,4)=128-reg budget
// spilled 90 regs.  Use (256,2)=256-reg budget.
// Round-5 lesson: un-prefetched loads serialize ~250cy L2 latency into every
// iteration (95us, all pipes <20%).  Fix: PING-PONG prefetch (two named reg
// sets, fully unrolled loop) -- zero rotation movs, compile-time addresses,
// each chunk's loads covered by a full chunk of compute.

typedef _Float16 f16x8 __attribute__((ext_vector_type(8)));
typedef _Float16 f16x4 __attribute__((ext_vector_type(4)));
typedef __fp16 fp16x2 __attribute__((ext_vector_type(2)));  // cvt_pkrtz ret type
typedef float f32x4 __attribute__((ext_vector_type(4)));

#define MFMA(a, b, c) __builtin_amdgcn_mfma_f32_16x16x32_f16((a), (b), (c), 0, 0, 0)
#define EXP2(x) __builtin_amdgcn_exp2f(x)
#define LOG2E 1.44269504088896340736f

// ---------------------------------------------------------------------------
// Kernel 1: fp32 -> f16 convert of x  (4096x1024)
// ---------------------------------------------------------------------------
__global__ __launch_bounds__(256) void k_convert_x(const float* __restrict__ x,
                                                   _Float16* __restrict__ xb) {
    int i = (blockIdx.x * 256 + threadIdx.x) * 4;
    float4 f = *(const float4*)(x + i);
    f16x4 o = {(_Float16)f.x, (_Float16)f.y, (_Float16)f.z, (_Float16)f.w};
    *(f16x4*)(xb + i) = o;
}

// ---------------------------------------------------------------------------
// Kernel 2: W (k-major [E][E]) -> W^T f16 ([3*E rows = n][E cols = k])
// ---------------------------------------------------------------------------
__global__ __launch_bounds__(256) void k_convert_wt(const float* __restrict__ Wq,
                                                    const float* __restrict__ Wk,
                                                    const float* __restrict__ Wv,
                                                    _Float16* __restrict__ wbt) {
    const int jz = blockIdx.z;
    const float* W = (jz == 0) ? Wq : (jz == 1) ? Wk : Wv;
    __shared__ float tile[64][65];
    const int k0 = blockIdx.y * 64, n0 = blockIdx.x * 64;
    for (int e = threadIdx.x; e < 4096; e += 256) {
        int r = e >> 6, c = e & 63;
        tile[r][c] = W[(k0 + r) * 1024 + n0 + c];
    }
    __syncthreads();
    for (int e = threadIdx.x; e < 4096; e += 256) {
        int r = e >> 6, c = e & 63;
        wbt[((size_t)jz * 1024 + n0 + r) * 1024 + k0 + c] = (_Float16)tile[c][r];
    }
}

// ---------------------------------------------------------------------------
// Kernel 3: fused QKV projection GEMM (Q scaled by log2e for exp2 downstream).
// ---------------------------------------------------------------------------
__global__ __launch_bounds__(256) void k_proj_gemm(const _Float16* __restrict__ xb,
                                                   const _Float16* __restrict__ wbt,
                                                   const float* __restrict__ bq,
                                                   const float* __restrict__ bk,
                                                   const float* __restrict__ bv,
                                                   _Float16* __restrict__ Qb,
                                                   _Float16* __restrict__ Kb,
                                                   _Float16* __restrict__ Vt) {
    const int n0 = blockIdx.x * 128;
    const int m0 = blockIdx.y * 128;
    __shared__ _Float16 As[128][40];
    __shared__ _Float16 Bs[128][40];
    const int tid = threadIdx.x;
    const int lane = tid & 63, wv = tid >> 6;
    const int l15 = lane & 15, quad = lane >> 4;
    const int wr = wv >> 1, wc = wv & 1;

    f32x4 acc[4][4] = {};
    for (int k0 = 0; k0 < 1024; k0 += 32) {
        __syncthreads();
        for (int j = 0; j < 2; ++j) {
            int chunk = tid + 256 * j;
            int row = chunk >> 2, c = chunk & 3;
            *(uint4*)&As[row][c * 8] = *(const uint4*)&xb[(size_t)(m0 + row) * 1024 + k0 + c * 8];
            *(uint4*)&Bs[row][c * 8] = *(const uint4*)&wbt[(size_t)(n0 + row) * 1024 + k0 + c * 8];
        }
        __syncthreads();
        f16x8 af[4], bf[4];
        for (int i = 0; i < 4; ++i) {
            af[i] = *(const f16x8*)&As[wr * 64 + i * 16 + l15][quad * 8];
            bf[i] = *(const f16x8*)&Bs[wc * 64 + i * 16 + l15][quad * 8];
        }
        for (int i = 0; i < 4; ++i)
            for (int j = 0; j < 4; ++j)
                acc[i][j] = MFMA(af[i], bf[j], acc[i][j]);
    }

    const int proj = n0 >> 10;
    const float* bias = (proj == 0) ? bq : (proj == 1) ? bk : bv;
    const float scale = (proj == 0) ? LOG2E : 1.0f;
    for (int j = 0; j < 4; ++j) {
        int n = n0 + wc * 64 + j * 16 + l15;
        int nn = n & 1023;
        float bsv = bias[nn];
        int h = nn >> 6, d = nn & 63;
        for (int i = 0; i < 4; ++i) {
            for (int r = 0; r < 4; ++r) {
                int t = m0 + wr * 64 + i * 16 + quad * 4 + r;
                int b = t >> 11, l = t & 2047;
                _Float16 val = (_Float16)((acc[i][j][r] + bsv) * scale);
                int bh = b * 16 + h;
                if (proj == 0)
                    Qb[((size_t)bh * 2048 + l) * 64 + d] = val;
                else if (proj == 1)
                    Kb[((size_t)bh * 2048 + l) * 64 + d] = val;
                else
                    Vt[((size_t)bh * 64 + d) * 2048 + l] = val;
            }
        }
    }
}

// ---------------------------------------------------------------------------
// Kernel 4: column stats d2_m = log2(sum_l 2^(S'[l,m])).
// Block = 64 m-cols of one head; 4 waves each own an l-quarter (512 l).
// K frags loop-invariant in regs; Q ping-pong-prefetched (chunk of 32 l).
// Partial exp-sums combined exactly in LDS at the end.  1024 blocks.
// ---------------------------------------------------------------------------
__global__ __launch_bounds__(256, 2) void k_stats(const _Float16* __restrict__ Qb,
                                                  const _Float16* __restrict__ Kb,
                                                  float* __restrict__ d2) {
    __shared__ float sred[4][4][64];            // [wave][s][lane] partials, 4KB
    const int id = blockIdx.x;                  // 1024 blocks
    const int wk = (id & 7) * 128 + (id >> 3);  // XCD swizzle: same-head -> same XCD
    const int bh = wk >> 5;                     // 32 heads
    const int mt = wk & 31;                     // 32 m-tiles of 64
    const int lane = threadIdx.x & 63, wv = threadIdx.x >> 6;
    const int l15 = lane & 15, quad = lane >> 4;
    const int m0 = mt * 64;
    const int lbase = wv * 512;                 // wave's l-quarter
    const size_t base = (size_t)bh * 2048 * 64;
    const _Float16* Kp = Kb + base;
    const _Float16* qb = Qb + base + (size_t)(lbase + l15) * 64 + quad * 8;

    // K fragments (X-operand rows = m): loop-invariant
    f16x8 bf[4][2];
    #pragma unroll
    for (int s = 0; s < 4; ++s) {
        bf[s][0] = *(const f16x8*)&Kp[(size_t)(m0 + s * 16 + l15) * 64 + quad * 8];
        bf[s][1] = *(const f16x8*)&Kp[(size_t)(m0 + s * 16 + l15) * 64 + 32 + quad * 8];
    }
    float rs[4] = {0.f, 0.f, 0.f, 0.f};
    f16x8 qd[2][2][2];  // [pingpong][lt][half] -- all indices compile-time

#define SLOAD(P, LC) do {                                          \
        qd[P][0][0] = *(const f16x8*)&qb[(LC)*64];                 \
        qd[P][0][1] = *(const f16x8*)&qb[(LC)*64 + 32];            \
        qd[P][1][0] = *(const f16x8*)&qb[(LC)*64 + 1024];          \
        qd[P][1][1] = *(const f16x8*)&qb[(LC)*64 + 1056];          \
    } while (0)

#define SCOMP(P) do {                                              \
        _Pragma("unroll")                                          \
        for (int s = 0; s < 4; ++s) {                              \
            _Pragma("unroll")                                      \
            for (int lt = 0; lt < 2; ++lt) {                       \
                f32x4 a = {};                                      \
                a = MFMA(qd[P][lt][0], bf[s][0], a);               \
                a = MFMA(qd[P][lt][1], bf[s][1], a);               \
                rs[s] += EXP2(a[0]) + EXP2(a[1]) +                 \
                         EXP2(a[2]) + EXP2(a[3]);                  \
            }                                                      \
        }                                                          \
    } while (0)

    SLOAD(0, 0);
    #pragma unroll
    for (int it = 0; it < 8; ++it) {
        const int cA = it * 64;
        const int cB = cA + 32;
        const int cN = (it < 7) ? cA + 64 : 0;  // last: dead in-bounds reload
        SLOAD(1, cB);
        SCOMP(0);
        SLOAD(0, cN);
        SCOMP(1);
    }
#undef SLOAD
#undef SCOMP

    // combine wave partials (exact: plain sum)
    #pragma unroll
    for (int s = 0; s < 4; ++s) sred[wv][s][lane] = rs[s];
    __syncthreads();
    if (wv == 0) {
        #pragma unroll
        for (int s = 0; s < 4; ++s) {
            float t = sred[0][s][lane] + sred[1][s][lane] + sred[2][s][lane] + sred[3][s][lane];
            t += __shfl_xor(t, 16, 64);
            t += __shfl_xor(t, 32, 64);
            rs[s] = t;
        }
        float myz = (quad == 0) ? rs[0] : (quad == 1) ? rs[1] : (quad == 2) ? rs[2] : rs[3];
        d2[bh * 2048 + m0 + quad * 16 + l15] = __builtin_amdgcn_logf(myz);  // v_log = log2
    }
}

// ---------------------------------------------------------------------------
// Kernel 5: output. Block = 64 l-rows of one head; 4 waves each own an
// m-quarter (512 m).  K/V/d2 ping-pong-prefetched a full 32-m chunk ahead
// (compile-time addresses, no rotation movs).  Swapped QK -> packed P ->
// ds_write_b64 (double-buffered Ps); swapped PV -> float4 epilogue.
// Partial O summed exactly at the end (PV linear in m).  1024 blocks.
// ---------------------------------------------------------------------------
__global__ __launch_bounds__(256, 2) void k_attn(const _Float16* __restrict__ Qb,
                                                 const _Float16* __restrict__ Kb,
                                                 const _Float16* __restrict__ Vt,
                                                 const float* __restrict__ d2,
                                                 float* __restrict__ out) {
    __shared__ _Float16 Ps[2][4][64][40];       // double-buffered P scratch, 40 KB
    __shared__ f32x4 obuf[3][4][64];            // [wave-1][lt][lane] combine, 12 KB
    const int id = blockIdx.x;                  // 1024 blocks
    const int wk = (id & 7) * 128 + (id >> 3);  // XCD swizzle
    const int bh = wk >> 5;                     // 32 heads
    const int ltile = wk & 31;                  // 32 l-tiles of 64
    const int b = bh >> 4, h = bh & 15;
    const int lane = threadIdx.x & 63, wv = threadIdx.x >> 6;
    const int l15 = lane & 15, quad = lane >> 4;
    const int l0 = ltile * 64;                  // block's 64 l-rows
    const int mbase = wv * 512;                 // wave's m-quarter
    const size_t base = (size_t)bh * 2048 * 64;
    const _Float16* Qp = Qb + base;
    // per-lane fragment base pointers (all loads = base + compile-time offset)
    const _Float16* kb = Kb + base + (size_t)(mbase + l15) * 64 + quad * 8;
    const _Float16* vb = Vt + base + (size_t)l15 * 2048 + mbase + quad * 8;
    const float* db = d2 + bh * 2048 + mbase + quad * 4;

    // Q fragments (Y-operand rows = l): loop-invariant
    f16x8 qf[4][2];
    #pragma unroll
    for (int lt = 0; lt < 4; ++lt) {
        qf[lt][0] = *(const f16x8*)&Qp[(size_t)(l0 + lt * 16 + l15) * 64 + quad * 8];
        qf[lt][1] = *(const f16x8*)&Qp[(size_t)(l0 + lt * 16 + l15) * 64 + 32 + quad * 8];
    }
    f32x4 oacc[4][4] = {};  // [dt][lt]: lane holds out[d=dt*16+quad*4+r][l=lt*16+l15]
    f16x8 kf[2][2][2];      // [pingpong][s][half]
    f16x8 vf[2][4];         // [pingpong][dt]
    f32x4 dv[2][2];         // [pingpong][s]

#define ALOAD(P, MC) do {                                          \
        kf[P][0][0] = *(const f16x8*)&kb[(MC)*64];                 \
        kf[P][0][1] = *(const f16x8*)&kb[(MC)*64 + 32];            \
        kf[P][1][0] = *(const f16x8*)&kb[(MC)*64 + 1024];          \
        kf[P][1][1] = *(const f16x8*)&kb[(MC)*64 + 1056];          \
        dv[P][0] = *(const f32x4*)&db[(MC)];                       \
        dv[P][1] = *(const f32x4*)&db[(MC) + 16];                  \
        vf[P][0] = *(const f16x8*)&vb[(MC)];                       \
        vf[P][1] = *(const f16x8*)&vb[(MC) + 32768];               \
        vf[P][2] = *(const f16x8*)&vb[(MC) + 65536];               \
        vf[P][3] = *(const f16x8*)&vb[(MC) + 98304];               \
    } while (0)

#define ACOMP(P) do {                                                         \
        _Pragma("unroll")                                                     \
        for (int s = 0; s < 2; ++s) {                                         \
            _Pragma("unroll")                                                 \
            for (int lt = 0; lt < 4; ++lt) {                                  \
                f32x4 a = {};                                                 \
                a = MFMA(kf[P][s][0], qf[lt][0], a);                          \
                a = MFMA(kf[P][s][1], qf[lt][1], a);                          \
                union { fp16x2 hh[2]; f16x4 v; } u;                           \
                u.hh[0] = __builtin_amdgcn_cvt_pkrtz(EXP2(a[0] - dv[P][s][0]),\
                                                     EXP2(a[1] - dv[P][s][1]));\
                u.hh[1] = __builtin_amdgcn_cvt_pkrtz(EXP2(a[2] - dv[P][s][2]),\
                                                     EXP2(a[3] - dv[P][s][3]));\
                *(f16x4*)&Ps[P][wv][lt * 16 + l15][s * 16 + quad * 4] = u.v;  \
            }                                                                 \
        }                                                                     \
        _Pragma("unroll")                                                     \
        for (int lt = 0; lt < 4; ++lt) {                                      \
            f16x8 pf = *(const f16x8*)&Ps[P][wv][lt * 16 + l15][quad * 8];    \
            _Pragma("unroll")                                                 \
            for (int dt = 0; dt < 4; ++dt)                                    \
                oacc[dt][lt] = MFMA(vf[P][dt], pf, oacc[dt][lt]);             \
        }                                                                     \
    } while (0)

    ALOAD(0, 0);
    #pragma unroll
    for (int it = 0; it < 8; ++it) {
        const int cA = it * 64;
        const int cB = cA + 32;
        const int cN = (it < 7) ? cA + 64 : 0;  // last: dead in-bounds reload
        ALOAD(1, cB);   // prefetch chunk B (covered by compute of A)
        ACOMP(0);
        ALOAD(0, cN);   // prefetch next A (covered by compute of B)
        ACOMP(1);
    }
#undef ALOAD
#undef ACOMP

    // combine the 4 m-quarter partials (exact) one dt-slab at a time, then
    // wave 0 writes float4-coalesced output.
    #pragma unroll
    for (int dt = 0; dt < 4; ++dt) {
        if (wv > 0) {
            #pragma unroll
            for (int lt = 0; lt < 4; ++lt) obuf[wv - 1][lt][lane] = oacc[dt][lt];
        }
        __syncthreads();
        if (wv == 0) {
            #pragma unroll
            for (int lt = 0; lt < 4; ++lt) {
                f32x4 o = oacc[dt][lt] + obuf[0][lt][lane] + obuf[1][lt][lane] + obuf[2][lt][lane];
                int l = l0 + lt * 16 + l15;
                float4 o4 = {o[0], o[1], o[2], o[3]};
                *(float4*)&out[((size_t)(b * 2048 + l)) * 1024 + h * 64 + dt * 16 + quad * 4] = o4;
            }
        }
        __syncthreads();
    }
}

// ---------------------------------------------------------------------------
// Workspace layout (bytes):
//  0        xb   : 4096*1024 f16          = 8 MB
//  8 MB     wbt  : 3072*1024 f16          = 6 MB
// 14 MB     Qb   : 32*2048*64 f16         = 8 MB   (pre-scaled by log2e)
// 22 MB     Kb   : 32*2048*64 f16         = 8 MB
// 30 MB     Vt   : 32*64*2048 f16         = 8 MB
// 38 MB     d2   : 32*2048 f32            = 256 KB (log2 of column expsum)
// ---------------------------------------------------------------------------
extern "C" void kernel_launch(void* const* d_in, const int* in_sizes, int n_in,
                              void* d_out, int out_size, void* d_ws, size_t ws_size,
                              hipStream_t stream) {
    const float* x  = (const float*)d_in[0];
    const float* Wq = (const float*)d_in[1];
    const float* bq = (const float*)d_in[2];
    const float* Wk = (const float*)d_in[3];
    const float* bk = (const float*)d_in[4];
    const float* Wv = (const float*)d_in[5];
    const float* bv = (const float*)d_in[6];
    float* out = (float*)d_out;

    char* w = (char*)d_ws;
    _Float16* xb  = (_Float16*)(w);
    _Float16* wbt = (_Float16*)(w + (size_t)(8 << 20));
    _Float16* Qb  = (_Float16*)(w + (size_t)(14 << 20));
    _Float16* Kb  = (_Float16*)(w + (size_t)(22 << 20));
    _Float16* Vt  = (_Float16*)(w + (size_t)(30 << 20));
    float* d2     = (float*)(w + (size_t)(38 << 20));

    k_convert_x<<<4096, 256, 0, stream>>>(x, xb);
    k_convert_wt<<<dim3(16, 16, 3), 256, 0, stream>>>(Wq, Wk, Wv, wbt);
    k_proj_gemm<<<dim3(24, 32), 256, 0, stream>>>(xb, wbt, bq, bk, bv, Qb, Kb, Vt);
    k_stats<<<1024, 256, 0, stream>>>(Qb, Kb, d2);
    k_attn<<<1024, 256, 0, stream>>>(Qb, Kb, Vt, d2, out);
}

// Round 7
// 231.261 us; speedup vs baseline: 2.0506x; 1.1171x over previous
//
#include <hip/hip_runtime.h>

// Problem: B=2, L=2048, E=1024, H=16, D=64
// softmax over QUERY axis (columns of the [L,M] score matrix per head).
//
// Softmax algebra: P[l,m] = 2^(S'[l,m] - d2_m), S' = log2(e)*S (folded into Q),
// d2_m = log2(sum_l 2^(S'[l,m])).  No max-subtraction: S ~ N(0,64) so
// |S'| < ~80 << 127 (f32 exp2 range); sum <= 2048*2^80 < f32 max.
//
// k_stats / k_attn: fragments read DIRECTLY from global (K+V = 512KB/head,
// L2-resident), ping-pong register prefetch (round-5/6 lesson), m-split /
// l-split 4 ways across waves, partials combined exactly at kernel end.
// k_proj_gemm (round-7): m97-structure staging -- global_load_lds width=16
// into LINEAR unpadded LDS (DMA writes wave-uniform base + lane*16; padding
// is illegal), 2-barrier K-loop.  Measured ladder: reg-staged ~300-500 TF ->
// global_load_lds ~874 TF on this exact tile shape.

typedef _Float16 f16x8 __attribute__((ext_vector_type(8)));
typedef _Float16 f16x4 __attribute__((ext_vector_type(4)));
typedef __fp16 fp16x2 __attribute__((ext_vector_type(2)));  // cvt_pkrtz ret type
typedef float f32x4 __attribute__((ext_vector_type(4)));

#define MFMA(a, b, c) __builtin_amdgcn_mfma_f32_16x16x32_f16((a), (b), (c), 0, 0, 0)
#define EXP2(x) __builtin_amdgcn_exp2f(x)
#define LOG2E 1.44269504088896340736f

// global -> LDS direct DMA, 16B per lane; dest = lds base + lane*16 (linear!)
#define GLOAD_LDS(gp, lp)                                                    \
    __builtin_amdgcn_global_load_lds(                                        \
        (const __attribute__((address_space(1))) void*)(const void*)(gp),    \
        (__attribute__((address_space(3))) void*)(void*)(lp), 16, 0, 0)

// ---------------------------------------------------------------------------
// Kernel 1: fp32 -> f16 convert of x  (4096x1024)
// ---------------------------------------------------------------------------
__global__ __launch_bounds__(256) void k_convert_x(const float* __restrict__ x,
                                                   _Float16* __restrict__ xb) {
    int i = (blockIdx.x * 256 + threadIdx.x) * 4;
    float4 f = *(const float4*)(x + i);
    f16x4 o = {(_Float16)f.x, (_Float16)f.y, (_Float16)f.z, (_Float16)f.w};
    *(f16x4*)(xb + i) = o;
}

// ---------------------------------------------------------------------------
// Kernel 2: W (k-major [E][E]) -> W^T f16 ([3*E rows = n][E cols = k])
// ---------------------------------------------------------------------------
__global__ __launch_bounds__(256) void k_convert_wt(const float* __restrict__ Wq,
                                                    const float* __restrict__ Wk,
                                                    const float* __restrict__ Wv,
                                                    _Float16* __restrict__ wbt) {
    const int jz = blockIdx.z;
    const float* W = (jz == 0) ? Wq : (jz == 1) ? Wk : Wv;
    __shared__ float tile[64][65];
    const int k0 = blockIdx.y * 64, n0 = blockIdx.x * 64;
    for (int e = threadIdx.x; e < 4096; e += 256) {
        int r = e >> 6, c = e & 63;
        tile[r][c] = W[(k0 + r) * 1024 + n0 + c];
    }
    __syncthreads();
    for (int e = threadIdx.x; e < 4096; e += 256) {
        int r = e >> 6, c = e & 63;
        wbt[((size_t)jz * 1024 + n0 + r) * 1024 + k0 + c] = (_Float16)tile[c][r];
    }
}

// ---------------------------------------------------------------------------
// Kernel 3: fused QKV projection GEMM (Q scaled by log2e for exp2 downstream).
// m97 structure: 128x128 tile, BK=32, 4 waves (2x2), global_load_lds staging
// into linear [128][32] LDS, 16 MFMA + 8 ds_read_b128 per K-step.
// ---------------------------------------------------------------------------
__global__ __launch_bounds__(256) void k_proj_gemm(const _Float16* __restrict__ xb,
                                                   const _Float16* __restrict__ wbt,
                                                   const float* __restrict__ bq,
                                                   const float* __restrict__ bk,
                                                   const float* __restrict__ bv,
                                                   _Float16* __restrict__ Qb,
                                                   _Float16* __restrict__ Kb,
                                                   _Float16* __restrict__ Vt) {
    const int n0 = blockIdx.x * 128;
    const int m0 = blockIdx.y * 128;
    __shared__ _Float16 As[128][32];  // LINEAR (no pad): global_load_lds dest
    __shared__ _Float16 Bs[128][32];
    const int tid = threadIdx.x;
    const int lane = tid & 63, wv = tid >> 6;
    const int l15 = lane & 15, quad = lane >> 4;
    const int wr = wv >> 1, wc = wv & 1;
    // staging map: wave covers 16 rows/issue; lane i -> row grp*16 + (i>>2),
    // col (i&3)*8 f16 = LDS offset i*16B from &As[grp*16][0]  (linear match)
    const int srow = lane >> 2, scol = (lane & 3) * 8;

    f32x4 acc[4][4] = {};
    for (int k0 = 0; k0 < 1024; k0 += 32) {
        __syncthreads();  // previous tile fully consumed
        #pragma unroll
        for (int j = 0; j < 2; ++j) {
            const int grp = j * 4 + wv;  // 0..7: 8 groups of 16 rows
            GLOAD_LDS(&xb[(size_t)(m0 + grp * 16 + srow) * 1024 + k0 + scol],
                      &As[grp * 16][0]);
            GLOAD_LDS(&wbt[(size_t)(n0 + grp * 16 + srow) * 1024 + k0 + scol],
                      &Bs[grp * 16][0]);
        }
        __syncthreads();  // compiler drains vmcnt before barrier
        f16x8 af[4], bf[4];
        #pragma unroll
        for (int i = 0; i < 4; ++i) {
            af[i] = *(const f16x8*)&As[wr * 64 + i * 16 + l15][quad * 8];
            bf[i] = *(const f16x8*)&Bs[wc * 64 + i * 16 + l15][quad * 8];
        }
        #pragma unroll
        for (int i = 0; i < 4; ++i)
            #pragma unroll
            for (int j = 0; j < 4; ++j)
                acc[i][j] = MFMA(af[i], bf[j], acc[i][j]);
    }

    const int proj = n0 >> 10;
    const float* bias = (proj == 0) ? bq : (proj == 1) ? bk : bv;
    const float scale = (proj == 0) ? LOG2E : 1.0f;
    for (int j = 0; j < 4; ++j) {
        int n = n0 + wc * 64 + j * 16 + l15;
        int nn = n & 1023;
        float bsv = bias[nn];
        int h = nn >> 6, d = nn & 63;
        for (int i = 0; i < 4; ++i) {
            for (int r = 0; r < 4; ++r) {
                int t = m0 + wr * 64 + i * 16 + quad * 4 + r;
                int b = t >> 11, l = t & 2047;
                _Float16 val = (_Float16)((acc[i][j][r] + bsv) * scale);
                int bh = b * 16 + h;
                if (proj == 0)
                    Qb[((size_t)bh * 2048 + l) * 64 + d] = val;
                else if (proj == 1)
                    Kb[((size_t)bh * 2048 + l) * 64 + d] = val;
                else
                    Vt[((size_t)bh * 64 + d) * 2048 + l] = val;
            }
        }
    }
}

// ---------------------------------------------------------------------------
// Kernel 4: column stats d2_m = log2(sum_l 2^(S'[l,m])).
// Block = 64 m-cols of one head; 4 waves each own an l-quarter (512 l).
// K frags loop-invariant in regs; Q ping-pong-prefetched (chunk of 32 l).
// Partial exp-sums combined exactly in LDS at the end.  1024 blocks.
// ---------------------------------------------------------------------------
__global__ __launch_bounds__(256, 2) void k_stats(const _Float16* __restrict__ Qb,
                                                  const _Float16* __restrict__ Kb,
                                                  float* __restrict__ d2) {
    __shared__ float sred[4][4][64];            // [wave][s][lane] partials, 4KB
    const int id = blockIdx.x;                  // 1024 blocks
    const int wk = (id & 7) * 128 + (id >> 3);  // XCD swizzle: same-head -> same XCD
    const int bh = wk >> 5;                     // 32 heads
    const int mt = wk & 31;                     // 32 m-tiles of 64
    const int lane = threadIdx.x & 63, wv = threadIdx.x >> 6;
    const int l15 = lane & 15, quad = lane >> 4;
    const int m0 = mt * 64;
    const int lbase = wv * 512;                 // wave's l-quarter
    const size_t base = (size_t)bh * 2048 * 64;
    const _Float16* Kp = Kb + base;
    const _Float16* qb = Qb + base + (size_t)(lbase + l15) * 64 + quad * 8;

    // K fragments (X-operand rows = m): loop-invariant
    f16x8 bf[4][2];
    #pragma unroll
    for (int s = 0; s < 4; ++s) {
        bf[s][0] = *(const f16x8*)&Kp[(size_t)(m0 + s * 16 + l15) * 64 + quad * 8];
        bf[s][1] = *(const f16x8*)&Kp[(size_t)(m0 + s * 16 + l15) * 64 + 32 + quad * 8];
    }
    float rs[4] = {0.f, 0.f, 0.f, 0.f};
    f16x8 qd[2][2][2];  // [pingpong][lt][half] -- all indices compile-time

#define SLOAD(P, LC) do {                                          \
        qd[P][0][0] = *(const f16x8*)&qb[(LC)*64];                 \
        qd[P][0][1] = *(const f16x8*)&qb[(LC)*64 + 32];            \
        qd[P][1][0] = *(const f16x8*)&qb[(LC)*64 + 1024];          \
        qd[P][1][1] = *(const f16x8*)&qb[(LC)*64 + 1056];          \
    } while (0)

#define SCOMP(P) do {                                              \
        _Pragma("unroll")                                          \
        for (int s = 0; s < 4; ++s) {                              \
            _Pragma("unroll")                                      \
            for (int lt = 0; lt < 2; ++lt) {                       \
                f32x4 a = {};                                      \
                a = MFMA(qd[P][lt][0], bf[s][0], a);               \
                a = MFMA(qd[P][lt][1], bf[s][1], a);               \
                rs[s] += EXP2(a[0]) + EXP2(a[1]) +                 \
                         EXP2(a[2]) + EXP2(a[3]);                  \
            }                                                      \
        }                                                          \
    } while (0)

    SLOAD(0, 0);
    #pragma unroll
    for (int it = 0; it < 8; ++it) {
        const int cA = it * 64;
        const int cB = cA + 32;
        const int cN = (it < 7) ? cA + 64 : 0;  // last: dead in-bounds reload
        SLOAD(1, cB);
        SCOMP(0);
        SLOAD(0, cN);
        SCOMP(1);
    }
#undef SLOAD
#undef SCOMP

    // combine wave partials (exact: plain sum)
    #pragma unroll
    for (int s = 0; s < 4; ++s) sred[wv][s][lane] = rs[s];
    __syncthreads();
    if (wv == 0) {
        #pragma unroll
        for (int s = 0; s < 4; ++s) {
            float t = sred[0][s][lane] + sred[1][s][lane] + sred[2][s][lane] + sred[3][s][lane];
            t += __shfl_xor(t, 16, 64);
            t += __shfl_xor(t, 32, 64);
            rs[s] = t;
        }
        float myz = (quad == 0) ? rs[0] : (quad == 1) ? rs[1] : (quad == 2) ? rs[2] : rs[3];
        d2[bh * 2048 + m0 + quad * 16 + l15] = __builtin_amdgcn_logf(myz);  // v_log = log2
    }
}

// ---------------------------------------------------------------------------
// Kernel 5: output. Block = 64 l-rows of one head; 4 waves each own an
// m-quarter (512 m).  K/V/d2 ping-pong-prefetched a full 32-m chunk ahead
// (compile-time addresses, no rotation movs).  Swapped QK -> packed P ->
// ds_write_b64 (double-buffered Ps); swapped PV -> float4 epilogue.
// Partial O summed exactly at the end (PV linear in m).  1024 blocks.
// ---------------------------------------------------------------------------
__global__ __launch_bounds__(256, 2) void k_attn(const _Float16* __restrict__ Qb,
                                                 const _Float16* __restrict__ Kb,
                                                 const _Float16* __restrict__ Vt,
                                                 const float* __restrict__ d2,
                                                 float* __restrict__ out) {
    __shared__ _Float16 Ps[2][4][64][40];       // double-buffered P scratch, 40 KB
    __shared__ f32x4 obuf[3][4][64];            // [wave-1][lt][lane] combine, 12 KB
    const int id = blockIdx.x;                  // 1024 blocks
    const int wk = (id & 7) * 128 + (id >> 3);  // XCD swizzle
    const int bh = wk >> 5;                     // 32 heads
    const int ltile = wk & 31;                  // 32 l-tiles of 64
    const int b = bh >> 4, h = bh & 15;
    const int lane = threadIdx.x & 63, wv = threadIdx.x >> 6;
    const int l15 = lane & 15, quad = lane >> 4;
    const int l0 = ltile * 64;                  // block's 64 l-rows
    const int mbase = wv * 512;                 // wave's m-quarter
    const size_t base = (size_t)bh * 2048 * 64;
    const _Float16* Qp = Qb + base;
    // per-lane fragment base pointers (all loads = base + compile-time offset)
    const _Float16* kb = Kb + base + (size_t)(mbase + l15) * 64 + quad * 8;
    const _Float16* vb = Vt + base + (size_t)l15 * 2048 + mbase + quad * 8;
    const float* db = d2 + bh * 2048 + mbase + quad * 4;

    // Q fragments (Y-operand rows = l): loop-invariant
    f16x8 qf[4][2];
    #pragma unroll
    for (int lt = 0; lt < 4; ++lt) {
        qf[lt][0] = *(const f16x8*)&Qp[(size_t)(l0 + lt * 16 + l15) * 64 + quad * 8];
        qf[lt][1] = *(const f16x8*)&Qp[(size_t)(l0 + lt * 16 + l15) * 64 + 32 + quad * 8];
    }
    f32x4 oacc[4][4] = {};  // [dt][lt]: lane holds out[d=dt*16+quad*4+r][l=lt*16+l15]
    f16x8 kf[2][2][2];      // [pingpong][s][half]
    f16x8 vf[2][4];         // [pingpong][dt]
    f32x4 dv[2][2];         // [pingpong][s]

#define ALOAD(P, MC) do {                                          \
        kf[P][0][0] = *(const f16x8*)&kb[(MC)*64];                 \
        kf[P][0][1] = *(const f16x8*)&kb[(MC)*64 + 32];            \
        kf[P][1][0] = *(const f16x8*)&kb[(MC)*64 + 1024];          \
        kf[P][1][1] = *(const f16x8*)&kb[(MC)*64 + 1056];          \
        dv[P][0] = *(const f32x4*)&db[(MC)];                       \
        dv[P][1] = *(const f32x4*)&db[(MC) + 16];                  \
        vf[P][0] = *(const f16x8*)&vb[(MC)];                       \
        vf[P][1] = *(const f16x8*)&vb[(MC) + 32768];               \
        vf[P][2] = *(const f16x8*)&vb[(MC) + 65536];               \
        vf[P][3] = *(const f16x8*)&vb[(MC) + 98304];               \
    } while (0)

#define ACOMP(P) do {                                                         \
        _Pragma("unroll")                                                     \
        for (int s = 0; s < 2; ++s) {                                         \
            _Pragma("unroll")                                                 \
            for (int lt = 0; lt < 4; ++lt) {                                  \
                f32x4 a = {};                                                 \
                a = MFMA(kf[P][s][0], qf[lt][0], a);                          \
                a = MFMA(kf[P][s][1], qf[lt][1], a);                          \
                union { fp16x2 hh[2]; f16x4 v; } u;                           \
                u.hh[0] = __builtin_amdgcn_cvt_pkrtz(EXP2(a[0] - dv[P][s][0]),\
                                                     EXP2(a[1] - dv[P][s][1]));\
                u.hh[1] = __builtin_amdgcn_cvt_pkrtz(EXP2(a[2] - dv[P][s][2]),\
                                                     EXP2(a[3] - dv[P][s][3]));\
                *(f16x4*)&Ps[P][wv][lt * 16 + l15][s * 16 + quad * 4] = u.v;  \
            }                                                                 \
        }                                                                     \
        _Pragma("unroll")                                                     \
        for (int lt = 0; lt < 4; ++lt) {                                      \
            f16x8 pf = *(const f16x8*)&Ps[P][wv][lt * 16 + l15][quad * 8];    \
            _Pragma("unroll")                                                 \
            for (int dt = 0; dt < 4; ++dt)                                    \
                oacc[dt][lt] = MFMA(vf[P][dt], pf, oacc[dt][lt]);             \
        }                                                                     \
    } while (0)

    ALOAD(0, 0);
    #pragma unroll
    for (int it = 0; it < 8; ++it) {
        const int cA = it * 64;
        const int cB = cA + 32;
        const int cN = (it < 7) ? cA + 64 : 0;  // last: dead in-bounds reload
        ALOAD(1, cB);   // prefetch chunk B (covered by compute of A)
        ACOMP(0);
        ALOAD(0, cN);   // prefetch next A (covered by compute of B)
        ACOMP(1);
    }
#undef ALOAD
#undef ACOMP

    // combine the 4 m-quarter partials (exact) one dt-slab at a time, then
    // wave 0 writes float4-coalesced output.
    #pragma unroll
    for (int dt = 0; dt < 4; ++dt) {
        if (wv > 0) {
            #pragma unroll
            for (int lt = 0; lt < 4; ++lt) obuf[wv - 1][lt][lane] = oacc[dt][lt];
        }
        __syncthreads();
        if (wv == 0) {
            #pragma unroll
            for (int lt = 0; lt < 4; ++lt) {
                f32x4 o = oacc[dt][lt] + obuf[0][lt][lane] + obuf[1][lt][lane] + obuf[2][lt][lane];
                int l = l0 + lt * 16 + l15;
                float4 o4 = {o[0], o[1], o[2], o[3]};
                *(float4*)&out[((size_t)(b * 2048 + l)) * 1024 + h * 64 + dt * 16 + quad * 4] = o4;
            }
        }
        __syncthreads();
    }
}

// ---------------------------------------------------------------------------
// Workspace layout (bytes):
//  0        xb   : 4096*1024 f16          = 8 MB
//  8 MB     wbt  : 3072*1024 f16          = 6 MB
// 14 MB     Qb   : 32*2048*64 f16         = 8 MB   (pre-scaled by log2e)
// 22 MB     Kb   : 32*2048*64 f16         = 8 MB
// 30 MB     Vt   : 32*64*2048 f16         = 8 MB
// 38 MB     d2   : 32*2048 f32            = 256 KB (log2 of column expsum)
// ---------------------------------------------------------------------------
extern "C" void kernel_launch(void* const* d_in, const int* in_sizes, int n_in,
                              void* d_out, int out_size, void* d_ws, size_t ws_size,
                              hipStream_t stream) {
    const float* x  = (const float*)d_in[0];
    const float* Wq = (const float*)d_in[1];
    const float* bq = (const float*)d_in[2];
    const float* Wk = (const float*)d_in[3];
    const float* bk = (const float*)d_in[4];
    const float* Wv = (const float*)d_in[5];
    const float* bv = (const float*)d_in[6];
    float* out = (float*)d_out;

    char* w = (char*)d_ws;
    _Float16* xb  = (_Float16*)(w);
    _Float16* wbt = (_Float16*)(w + (size_t)(8 << 20));
    _Float16* Qb  = (_Float16*)(w + (size_t)(14 << 20));
    _Float16* Kb  = (_Float16*)(w + (size_t)(22 << 20));
    _Float16* Vt  = (_Float16*)(w + (size_t)(30 << 20));
    float* d2     = (float*)(w + (size_t)(38 << 20));

    k_convert_x<<<4096, 256, 0, stream>>>(x, xb);
    k_convert_wt<<<dim3(16, 16, 3), 256, 0, stream>>>(Wq, Wk, Wv, wbt);
    k_proj_gemm<<<dim3(24, 32), 256, 0, stream>>>(xb, wbt, bq, bk, bv, Qb, Kb, Vt);
    k_stats<<<1024, 256, 0, stream>>>(Qb, Kb, d2);
    k_attn<<<1024, 256, 0, stream>>>(Qb, Kb, Vt, d2, out);
}